// Round 15
// baseline (280.461 us; speedup 1.0000x reference)
//
#include <hip/hip_runtime.h>
#include <stdint.h>

#define T_SEQ   2048
#define DMODEL  1024
#define NHEADS  16
#define HDIM    64
#define BATCH   4
#define MROWS   (BATCH * T_SEQ)   // 8192
// Q pre-scale: 1/sqrt(64) * log2(e)  (softmax runs in exp2 domain)
#define QSCALE  0.18033688011112042f
// defer-max threshold (log2 units): skip O/l rescale unless max grew by >6
#define DEFER_THR 6.0f

typedef __attribute__((ext_vector_type(4))) short bf16x4;
typedef __attribute__((ext_vector_type(8))) short bf16x8;
typedef __attribute__((ext_vector_type(4))) float f32x4;

__device__ __forceinline__ unsigned short f2b(float f) {
    union { float f; unsigned int i; } x;
    x.f = f;
    unsigned int r = x.i + 0x7FFFu + ((x.i >> 16) & 1u);  // RNE
    return (unsigned short)(r >> 16);
}

// raw v_exp_f32 (input in log2 domain)
__device__ __forceinline__ float fexp2(float x) {
#if __has_builtin(__builtin_amdgcn_exp2f)
    return __builtin_amdgcn_exp2f(x);
#else
    return __expf(x * 0.6931471805599453f);
#endif
}

// pack two fp32 -> packed bf16 pair (low = a, high = b)
__device__ __forceinline__ unsigned int pack2(float a, float b) {
#if __has_builtin(__builtin_amdgcn_cvt_pk_bf16_f32)
    auto r = __builtin_amdgcn_cvt_pk_bf16_f32(a, b);
    unsigned int u;
    __builtin_memcpy(&u, &r, 4);
    return u;
#else
    return ((unsigned int)f2b(a)) | (((unsigned int)f2b(b)) << 16);
#endif
}

// tree max of a 4x f32x4 tile (depth 4; clang fuses pairs to v_max3 where it can)
__device__ __forceinline__ float max16(const f32x4 s[4]) {
    const float a = fmaxf(fmaxf(s[0][0], s[0][1]), fmaxf(s[0][2], s[0][3]));
    const float b = fmaxf(fmaxf(s[1][0], s[1][1]), fmaxf(s[1][2], s[1][3]));
    const float c = fmaxf(fmaxf(s[2][0], s[2][1]), fmaxf(s[2][2], s[2][3]));
    const float d = fmaxf(fmaxf(s[3][0], s[3][1]), fmaxf(s[3][2], s[3][3]));
    return fmaxf(fmaxf(a, b), fmaxf(c, d));
}

// online softmax (exp2 domain) for one 16x(4x16) score tile
__device__ __forceinline__ void online_softmax(
    const f32x4 sg[4], float& m_, float& l_, f32x4 o_[4], bf16x4 pf_[4])
{
    float mc = max16(sg);
    mc = fmaxf(mc, __shfl_xor(mc, 16));
    mc = fmaxf(mc, __shfl_xor(mc, 32));
    if (__any(mc > m_ + DEFER_THR)) {          // defer-max: rescale rarely
        const float mn    = fmaxf(m_, mc);
        const float alpha = fexp2(m_ - mn);
        l_ *= alpha;
        #pragma unroll
        for (int dt = 0; dt < 4; dt++)
            #pragma unroll
            for (int r = 0; r < 4; r++) o_[dt][r] *= alpha;
        m_ = mn;
    }
    float ps = 0.f;
    #pragma unroll
    for (int s = 0; s < 4; s++) {
        const float p0 = fexp2(sg[s][0] - m_);
        const float p1 = fexp2(sg[s][1] - m_);
        const float p2 = fexp2(sg[s][2] - m_);
        const float p3 = fexp2(sg[s][3] - m_);
        ps += (p0 + p1) + (p2 + p3);
        uint2 u;
        u.x = pack2(p0, p1);
        u.y = pack2(p2, p3);
        pf_[s] = *(bf16x4*)&u;
    }
    ps += __shfl_xor(ps, 16);
    ps += __shfl_xor(ps, 32);
    l_ += ps;
}

// async global->LDS, 16 B per lane; dest = lds base (wave-uniform) + lane*16
__device__ __forceinline__ void gl_lds16(const unsigned short* g, unsigned short* l) {
    __builtin_amdgcn_global_load_lds(
        (const __attribute__((address_space(1))) void*)g,
        (__attribute__((address_space(3))) void*)l,
        16, 0, 0);
}

// ---------------------------------------------------------------------------
// fp32 -> bf16 elementwise convert
// ---------------------------------------------------------------------------
__global__ __launch_bounds__(256) void cvt_bf16(
    const float* __restrict__ in, unsigned short* __restrict__ out, int n)
{
    const int i = (blockIdx.x * 256 + threadIdx.x) * 4;
    if (i + 3 < n) {
        const float4 v = *(const float4*)(in + i);
        ushort4 o;
        o.x = f2b(v.x); o.y = f2b(v.y); o.z = f2b(v.z); o.w = f2b(v.w);
        *(ushort4*)(out + i) = o;
    }
}

// ---------------------------------------------------------------------------
// fp32 [K][N] -> bf16 [N][K] transpose+convert, 32x32 LDS tile
// ---------------------------------------------------------------------------
__global__ __launch_bounds__(256) void cvt_tr(
    const float* __restrict__ W, unsigned short* __restrict__ WT, int K, int N)
{
    __shared__ unsigned short s[32][33];
    const int n0 = blockIdx.x * 32, k0 = blockIdx.y * 32;
    const int tx = threadIdx.x & 31, ty = threadIdx.x >> 5;   // ty 0..7
    #pragma unroll
    for (int i = 0; i < 4; i++)
        s[ty + 8 * i][tx] = f2b(W[(size_t)(k0 + ty + 8 * i) * N + n0 + tx]);
    __syncthreads();
    #pragma unroll
    for (int i = 0; i < 4; i++)
        WT[(size_t)(n0 + ty + 8 * i) * K + k0 + tx] = s[tx][ty + 8 * i];
}

// ---------------------------------------------------------------------------
// bf16 MFMA GEMM: C[M][NCOLS] = A[M][KD] * BT[NCOLS][KD]^T + bias[NCOLS]
// 128x128 tile, BK=64, 256 thr = 4 waves (2x2). R20 EXACT (verified 267.3):
// compile-time KD/NCOLS + hoisted staging pointers (R17), XOR swizzle
// chunk^(row&7) (0 conflicts), T1 XCD remap (FETCH 76->49MB).
// R23's counted-vmcnt 2-buffer pipeline REVERTED: measured neutral (267.5)
// -> the per-K-step drain is NOT the binder even at ~2 blocks/CU (m99/m100
// null replicates). Keep the simpler 32KB single-buffer form.
// ---------------------------------------------------------------------------
template<int KD, int NCOLS, int MODE>
__global__ __launch_bounds__(256) void gemm_mfma(
    const unsigned short* __restrict__ A,
    const unsigned short* __restrict__ BT,
    const float* __restrict__ bias,
    unsigned short* __restrict__ Oq,
    unsigned short* __restrict__ Ok,
    unsigned short* __restrict__ Ov,
    float* __restrict__ Of)
{
    __shared__ __align__(16) unsigned short aS[128 * 64];
    __shared__ __align__(16) unsigned short bS[128 * 64];

    const int tid  = threadIdx.x;
    const int lane = tid & 63;
    const int wave = tid >> 6;
    const int row  = lane & 15;
    const int quad = lane >> 4;
    const int wm   = wave >> 1;
    const int wn   = wave & 1;

    // T1 XCD remap: HW dispatches linear id x-major, round-robin over 8 XCDs.
    constexpr int NT  = NCOLS / 128;          // N-tiles (24 or 8)
    constexpr int MT8 = (MROWS / 128) / 8;    // M-tiles per XCD chunk = 8
    const int orig = blockIdx.x + blockIdx.y * NT;
    const int xcd  = orig & 7;
    const int pos  = orig >> 3;               // position within XCD chunk
    const int nt   = pos >> 3;                // N-tile (pos / MT8)
    const int mtl  = pos & (MT8 - 1);         // local M-tile
    const int m0   = (xcd * MT8 + mtl) * 128;
    const int n0   = nt * 128;

    // staging geometry: one gload = 64 lanes x 16B = 8 rows x 64 k (128B/row)
    const int srow = lane >> 3;            // 0..7  local row
    const int c8   = lane & 7;             // 0..7  dest chunk (16B units)
    const int csw  = c8 ^ srow;            // pre-swizzled SOURCE chunk

    // hoisted global staging pointers (advance by 64 elements per K-step)
    const unsigned short* aG = A  + (size_t)(m0 + wave * 8 + srow) * KD + csw * 8;
    const unsigned short* bG = BT + (size_t)(n0 + wave * 8 + srow) * KD + csw * 8;

    f32x4 acc[4][4];
    const f32x4 z = {0.f, 0.f, 0.f, 0.f};
    #pragma unroll
    for (int i = 0; i < 4; i++)
        #pragma unroll
        for (int j = 0; j < 4; j++) acc[i][j] = z;

    for (int k0 = 0; k0 < KD; k0 += 64) {
        __syncthreads();   // all waves done reading previous tile
        #pragma unroll
        for (int c = 0; c < 4; c++) {
            gl_lds16(aG + c * (32 * KD), &aS[c * 2048 + wave * 512]);
            gl_lds16(bG + c * (32 * KD), &bS[c * 2048 + wave * 512]);
        }
        __syncthreads();   // drains vmcnt -> LDS valid
        aG += 64;
        bG += 64;

        #pragma unroll
        for (int ks = 0; ks < 2; ks++) {
            bf16x8 af[4], bf[4];
            const int cp = ((ks * 4 + quad) ^ (row & 7)) * 8;   // swizzled read chunk
            #pragma unroll
            for (int t = 0; t < 4; t++) {
                af[t] = *(const bf16x8*)(aS + (wm * 64 + t * 16 + row) * 64 + cp);
                bf[t] = *(const bf16x8*)(bS + (wn * 64 + t * 16 + row) * 64 + cp);
            }
            #pragma unroll
            for (int i = 0; i < 4; i++)
                #pragma unroll
                for (int j = 0; j < 4; j++)
                    acc[i][j] = __builtin_amdgcn_mfma_f32_16x16x32_bf16(af[i], bf[j], acc[i][j], 0, 0, 0);
        }
    }

    if (MODE == 0) {
        #pragma unroll
        for (int j = 0; j < 4; j++) {
            const int n  = n0 + wn * 64 + j * 16 + row;
            const float bi = bias[n];
            const int which = n >> 10;
            const int rem   = n & 1023;
            const int h     = rem >> 6;
            const int d     = rem & 63;
            #pragma unroll
            for (int i = 0; i < 4; i++) {
                const int mbase = m0 + wm * 64 + i * 16 + quad * 4;
                #pragma unroll
                for (int r = 0; r < 4; r++) {
                    const int m = mbase + r;
                    const int b = m >> 11;
                    const int t = m & 2047;
                    const int bh = b * NHEADS + h;
                    const float v = acc[i][j][r] + bi;
                    if (which == 0) {
                        Oq[((size_t)bh * T_SEQ + t) * HDIM + d] = f2b(v * QSCALE);
                    } else if (which == 1) {
                        Ok[((size_t)bh * T_SEQ + t) * HDIM + d] = f2b(v);
                    } else {
                        Ov[((size_t)bh * HDIM + d) * T_SEQ + t] = f2b(v);
                    }
                }
            }
        }
    } else {
        #pragma unroll
        for (int j = 0; j < 4; j++) {
            const int n  = n0 + wn * 64 + j * 16 + row;
            const float bi = bias[n];
            #pragma unroll
            for (int i = 0; i < 4; i++) {
                const int mbase = m0 + wm * 64 + i * 16 + quad * 4;
                #pragma unroll
                for (int r = 0; r < 4; r++)
                    Of[(size_t)(mbase + r) * NCOLS + n] = acc[i][j][r] + bi;
            }
        }
    }
}

// ---------------------------------------------------------------------------
// MFMA flash attention — R24: R19 structure (verified 85.9us) with ONE
// change: LDS stride 72 -> 64 + XOR chunk swizzle on the PER-LANE ds_write
// staging path (no gl_lds16 wave-uniform-dest constraint, unlike R21).
// Bank math: stride-72 b128 K-read had bank base 4(row+quad)%32 -> 8-way
// conflict (2.94x, m136) = the 4.2M conflict-cycles (~7us). Swizzle: thread
// writes global chunk c0 of row r to LDS slot c0^(r&7); K-read fetches
// chunk g at slot g^(row&7) (exact GEMM pattern, measured 0 conflicts);
// V-read chunk (s*2+(quad>>1))^(row&7) + (quad&1)*4 sub-offset (within the
// 8-short chunk). Rows +32 preserve r&7 -> same involution. Everything
// else R19 verbatim: 1 tile/wave, one-sided blocks, grid (64,16),
// longest-first, defer-max + tree-max, no setprio.
// ---------------------------------------------------------------------------
__global__ __launch_bounds__(512, 4) void attn_mfma(
    const unsigned short* __restrict__ Q,   // [bh][t][64] bf16 (scaled, log2e)
    const unsigned short* __restrict__ K,   // [bh][t][64] bf16
    const unsigned short* __restrict__ VT,  // [bh][64][T] bf16
    unsigned short* __restrict__ Out)       // [B*T][DMODEL] bf16
{
    __shared__ __align__(16) unsigned short kS[2][64 * 64];
    __shared__ __align__(16) unsigned short vS[2][64 * 64];

    const int tid  = threadIdx.x;
    const int lane = tid & 63;
    const int wave = tid >> 6;       // 0..7
    const int row  = lane & 15;
    const int quad = lane >> 4;

    const int bh = blockIdx.x;
    const int b  = bh >> 4;
    const int h  = bh & 15;
    const int i  = 15 - (int)blockIdx.y;       // longest blocks first
    const int q0 = 128 * i + 16 * wave;        // this wave's 16 q-rows
    const int kend = 128 * i + 128;            // WG-uniform loop bound

    const size_t qkbase = (size_t)bh * T_SEQ * HDIM;
    const size_t vtbase = (size_t)bh * HDIM * T_SEQ;

    // staging geometry: 512 threads cover one 64x64 tile per operand.
    // XOR swizzle: thread's global chunk c0 of row krow0 lands in slot
    // c0 ^ (krow0&7)  ->  LDS slot s holds global chunk s ^ (r&7).
    const int krow0 = tid >> 3;          // 0..63
    const int c0    = tid & 7;           // 0..7
    const int lds0  = krow0 * 64 + (c0 ^ (krow0 & 7)) * 8;
    const int flat0 = tid * 8;           // = krow0*64 + c0*8 (global, linear)

    // Q fragments
    const unsigned short* qp = Q + qkbase + (size_t)(q0 + row) * HDIM + quad * 8;
    const bf16x8 qf0 = *(const bf16x8*)qp;
    const bf16x8 qf1 = *(const bf16x8*)(qp + 32);

    // hoisted swizzled read chunk offsets (shorts)
    const int r7   = row & 7;
    const int swk0 = (quad ^ r7) * 8;           // K chunk quad   (hdim 0..31)
    const int swk1 = ((quad + 4) ^ r7) * 8;     // K chunk quad+4 (hdim 32..63)

    const f32x4 z = {0.f, 0.f, 0.f, 0.f};
    f32x4 o[4] = {z, z, z, z};
    float m_ = -1e30f, l_ = 0.f;

    // prefetch tile 0
    uint4 pk0 = *(const uint4*)(K  + qkbase + flat0);
    uint4 pv0 = *(const uint4*)(VT + vtbase + (size_t)krow0 * T_SEQ + c0 * 8);

    int buf = 0;
    for (int kb = 0; kb < kend; kb += 64) {
        // write staged tile to LDS[buf] (swizzled slots)
        *(uint4*)&kS[buf][lds0] = pk0;
        *(uint4*)&vS[buf][lds0] = pv0;
        __syncthreads();

        // prefetch next tile (overlaps with compute below)
        if (kb + 64 < kend) {
            const int kn = kb + 64;
            pk0 = *(const uint4*)(K  + qkbase + (size_t)kn * HDIM + flat0);
            pv0 = *(const uint4*)(VT + vtbase + (size_t)krow0 * T_SEQ + kn + c0 * 8);
        }

        const bool act = (kb <= q0);         // wave-uniform

        if (act) {
            // ---- QK^T from LDS K tile (swizzled reads, 0-conflict pattern) ----
            f32x4 sg[4];
            bf16x4 pf[4];
            #pragma unroll
            for (int s = 0; s < 4; s++) {
                const int kbs = kb + s * 16;
                if (kbs <= q0) {
                    const unsigned short* kp = &kS[buf][(s * 16 + row) * 64];
                    const bf16x8 kf0 = *(const bf16x8*)(kp + swk0);
                    const bf16x8 kf1 = *(const bf16x8*)(kp + swk1);
                    f32x4 t = z;
                    t = __builtin_amdgcn_mfma_f32_16x16x32_bf16(kf0, qf0, t, 0, 0, 0);
                    t = __builtin_amdgcn_mfma_f32_16x16x32_bf16(kf1, qf1, t, 0, 0, 0);
                    if (kbs == q0) {
                        #pragma unroll
                        for (int r = 0; r < 4; r++)
                            if (quad * 4 + r > row) t[r] = -1e30f;
                    }
                    sg[s] = t;
                } else {
                    #pragma unroll
                    for (int r = 0; r < 4; r++) sg[s][r] = -1e30f;
                }
            }
            online_softmax(sg, m_, l_, o, pf);

            // ---- PV from LDS V^T tile (swizzled reads) ----
            #pragma unroll
            for (int s = 0; s < 4; s++) {
                const int kbs = kb + s * 16;
                if (kbs <= q0) {
                    const int cv = ((s * 2 + (quad >> 1)) ^ r7) * 8 + (quad & 1) * 4;
                    #pragma unroll
                    for (int dt = 0; dt < 4; dt++) {
                        const bf16x4 vf = *(const bf16x4*)&vS[buf][(dt * 16 + row) * 64 + cv];
                        o[dt] = __builtin_amdgcn_mfma_f32_16x16x16bf16_1k(vf, pf[s], o[dt], 0, 0, 0);
                    }
                }
            }
        }

        buf ^= 1;
    }

    // ---- epilogue ----
    {
        const float rl = 1.f / l_;
        unsigned short* op = Out + ((size_t)(b * T_SEQ + q0 + row)) * DMODEL + h * HDIM + quad * 4;
        #pragma unroll
        for (int dt = 0; dt < 4; dt++) {
            uint2 u;
            u.x = pack2(o[dt][0] * rl, o[dt][1] * rl);
            u.y = pack2(o[dt][2] * rl, o[dt][3] * rl);
            *(uint2*)(op + dt * 16) = u;
        }
    }
}

extern "C" void kernel_launch(void* const* d_in, const int* in_sizes, int n_in,
                              void* d_out, int out_size, void* d_ws, size_t ws_size,
                              hipStream_t stream)
{
    const float* x    = (const float*)d_in[0];
    const float* Wqkv = (const float*)d_in[1];
    const float* bqkv = (const float*)d_in[2];
    const float* Wout = (const float*)d_in[3];
    const float* bout = (const float*)d_in[4];
    float* out = (float*)d_out;

    // workspace (MiB offsets): xb 0..16 | WqkvT 16..22 | WoutT 22..24 |
    // Qb 24..40 | Kb 40..56 | Vt 56..72 | Ab 72..88
    char* ws = (char*)d_ws;
    unsigned short* xb    = (unsigned short*)(ws + (size_t)0  * 1024 * 1024);
    unsigned short* WqkvT = (unsigned short*)(ws + (size_t)16 * 1024 * 1024);
    unsigned short* WoutT = (unsigned short*)(ws + (size_t)22 * 1024 * 1024);
    unsigned short* Qb    = (unsigned short*)(ws + (size_t)24 * 1024 * 1024);
    unsigned short* Kb    = (unsigned short*)(ws + (size_t)40 * 1024 * 1024);
    unsigned short* Vt    = (unsigned short*)(ws + (size_t)56 * 1024 * 1024);
    unsigned short* Ab    = (unsigned short*)(ws + (size_t)72 * 1024 * 1024);

    // 0) converts / transposes
    cvt_bf16<<<dim3(MROWS * DMODEL / 1024), 256, 0, stream>>>(x, xb, MROWS * DMODEL);
    cvt_tr<<<dim3(3 * DMODEL / 32, DMODEL / 32), 256, 0, stream>>>(Wqkv, WqkvT, DMODEL, 3 * DMODEL);
    cvt_tr<<<dim3(DMODEL / 32, DMODEL / 32), 256, 0, stream>>>(Wout, WoutT, DMODEL, DMODEL);

    // 1) qkv = x @ W_qkv + b_qkv -> Qb (scaled, log2e folded), Kb, Vt
    gemm_mfma<DMODEL, 3 * DMODEL, 0><<<dim3(3 * DMODEL / 128, MROWS / 128), 256, 0, stream>>>(
        xb, WqkvT, bqkv, Qb, Kb, Vt, nullptr);

    // 2) causal MFMA flash attention -> Ab bf16 (16 blocks/head, 8 waves, 1 tile/wave)
    attn_mfma<<<dim3(BATCH * NHEADS, 16), 512, 0, stream>>>(Qb, Kb, Vt, Ab);

    // 3) out = Ab @ W_out + b_out (fp32 out)
    gemm_mfma<DMODEL, DMODEL, 1><<<dim3(DMODEL / 128, MROWS / 128), 256, 0, stream>>>(
        Ab, WoutT, bout, nullptr, nullptr, nullptr, out);
}

// Round 16
// 264.577 us; speedup vs baseline: 1.0600x; 1.0600x over previous
//
#include <hip/hip_runtime.h>
#include <stdint.h>

#define T_SEQ   2048
#define DMODEL  1024
#define NHEADS  16
#define HDIM    64
#define BATCH   4
#define MROWS   (BATCH * T_SEQ)   // 8192
// Q pre-scale: 1/sqrt(64) * log2(e)  (softmax runs in exp2 domain)
#define QSCALE  0.18033688011112042f
// defer-max threshold (log2 units): skip O/l rescale unless max grew by >6
#define DEFER_THR 6.0f

typedef __attribute__((ext_vector_type(4))) short bf16x4;
typedef __attribute__((ext_vector_type(8))) short bf16x8;
typedef __attribute__((ext_vector_type(4))) float f32x4;

__device__ __forceinline__ unsigned short f2b(float f) {
    union { float f; unsigned int i; } x;
    x.f = f;
    unsigned int r = x.i + 0x7FFFu + ((x.i >> 16) & 1u);  // RNE
    return (unsigned short)(r >> 16);
}

// raw v_exp_f32 (input in log2 domain)
__device__ __forceinline__ float fexp2(float x) {
#if __has_builtin(__builtin_amdgcn_exp2f)
    return __builtin_amdgcn_exp2f(x);
#else
    return __expf(x * 0.6931471805599453f);
#endif
}

// pack two fp32 -> packed bf16 pair (low = a, high = b)
__device__ __forceinline__ unsigned int pack2(float a, float b) {
#if __has_builtin(__builtin_amdgcn_cvt_pk_bf16_f32)
    auto r = __builtin_amdgcn_cvt_pk_bf16_f32(a, b);
    unsigned int u;
    __builtin_memcpy(&u, &r, 4);
    return u;
#else
    return ((unsigned int)f2b(a)) | (((unsigned int)f2b(b)) << 16);
#endif
}

// tree max of a 4x f32x4 tile (depth 4; clang fuses pairs to v_max3 where it can)
__device__ __forceinline__ float max16(const f32x4 s[4]) {
    const float a = fmaxf(fmaxf(s[0][0], s[0][1]), fmaxf(s[0][2], s[0][3]));
    const float b = fmaxf(fmaxf(s[1][0], s[1][1]), fmaxf(s[1][2], s[1][3]));
    const float c = fmaxf(fmaxf(s[2][0], s[2][1]), fmaxf(s[2][2], s[2][3]));
    const float d = fmaxf(fmaxf(s[3][0], s[3][1]), fmaxf(s[3][2], s[3][3]));
    return fmaxf(fmaxf(a, b), fmaxf(c, d));
}

// online softmax (exp2 domain) for one 16x(4x16) score tile
__device__ __forceinline__ void online_softmax(
    const f32x4 sg[4], float& m_, float& l_, f32x4 o_[4], bf16x4 pf_[4])
{
    float mc = max16(sg);
    mc = fmaxf(mc, __shfl_xor(mc, 16));
    mc = fmaxf(mc, __shfl_xor(mc, 32));
    if (__any(mc > m_ + DEFER_THR)) {          // defer-max: rescale rarely
        const float mn    = fmaxf(m_, mc);
        const float alpha = fexp2(m_ - mn);
        l_ *= alpha;
        #pragma unroll
        for (int dt = 0; dt < 4; dt++)
            #pragma unroll
            for (int r = 0; r < 4; r++) o_[dt][r] *= alpha;
        m_ = mn;
    }
    float ps = 0.f;
    #pragma unroll
    for (int s = 0; s < 4; s++) {
        const float p0 = fexp2(sg[s][0] - m_);
        const float p1 = fexp2(sg[s][1] - m_);
        const float p2 = fexp2(sg[s][2] - m_);
        const float p3 = fexp2(sg[s][3] - m_);
        ps += (p0 + p1) + (p2 + p3);
        uint2 u;
        u.x = pack2(p0, p1);
        u.y = pack2(p2, p3);
        pf_[s] = *(bf16x4*)&u;
    }
    ps += __shfl_xor(ps, 16);
    ps += __shfl_xor(ps, 32);
    l_ += ps;
}

// async global->LDS, 16 B per lane; dest = lds base (wave-uniform) + lane*16
__device__ __forceinline__ void gl_lds16(const unsigned short* g, unsigned short* l) {
    __builtin_amdgcn_global_load_lds(
        (const __attribute__((address_space(1))) void*)g,
        (__attribute__((address_space(3))) void*)l,
        16, 0, 0);
}

// ---------------------------------------------------------------------------
// R25 merged prep kernel: one launch replaces {cvt_bf16, cvt_tr(Wqkv),
// cvt_tr(Wout)} — attacks the ~50us of inter-dispatch gap implied by
// (sum of kernel durs ~213us) vs (graph total 267us). Block-id ranges:
//   [0, 8192)            : x fp32 -> xb bf16 (1024 elems/block)
//   [8192, 8192+3072)    : Wqkv [1024][3072] -> WqkvT [3072][1024] 32x32 tile
//   [11264, 11264+1024)  : Wout [1024][1024] -> WoutT [1024][1024] 32x32 tile
// Branch is block-uniform; inner code identical to the verified kernels.
// ---------------------------------------------------------------------------
__device__ __forceinline__ void tr_tile(
    const float* __restrict__ W, unsigned short* __restrict__ WT,
    int K, int N, int n0, int k0, unsigned short (*s)[33])
{
    const int tx = threadIdx.x & 31, ty = threadIdx.x >> 5;   // ty 0..7
    #pragma unroll
    for (int i = 0; i < 4; i++)
        s[ty + 8 * i][tx] = f2b(W[(size_t)(k0 + ty + 8 * i) * N + n0 + tx]);
    __syncthreads();
    #pragma unroll
    for (int i = 0; i < 4; i++)
        WT[(size_t)(n0 + ty + 8 * i) * K + k0 + tx] = s[tx][ty + 8 * i];
}

__global__ __launch_bounds__(256) void prep(
    const float* __restrict__ x,    unsigned short* __restrict__ xb,
    const float* __restrict__ Wqkv, unsigned short* __restrict__ WqkvT,
    const float* __restrict__ Wout, unsigned short* __restrict__ WoutT)
{
    __shared__ unsigned short s[32][33];
    const int id = blockIdx.x;
    if (id < 8192) {
        const int i = (id * 256 + threadIdx.x) * 4;   // max i+3 = 8388607 < 2^23 OK
        const float4 v = *(const float4*)(x + i);
        ushort4 o;
        o.x = f2b(v.x); o.y = f2b(v.y); o.z = f2b(v.z); o.w = f2b(v.w);
        *(ushort4*)(xb + i) = o;
    } else if (id < 8192 + 3072) {
        const int id2 = id - 8192;
        tr_tile(Wqkv, WqkvT, DMODEL, 3 * DMODEL, (id2 % 96) * 32, (id2 / 96) * 32, s);
    } else {
        const int id3 = id - (8192 + 3072);
        tr_tile(Wout, WoutT, DMODEL, DMODEL, (id3 & 31) * 32, (id3 >> 5) * 32, s);
    }
}

// ---------------------------------------------------------------------------
// bf16 MFMA GEMM: C[M][NCOLS] = A[M][KD] * BT[NCOLS][KD]^T + bias[NCOLS]
// 128x128 tile, BK=64, 256 thr = 4 waves (2x2). R20 EXACT (verified 267.3):
// compile-time KD/NCOLS + hoisted staging pointers (R17), XOR swizzle
// chunk^(row&7) (0 conflicts), T1 XCD remap (FETCH 76->49MB).
// R23 counted-vmcnt pipeline refuted (neutral); R18 8-phase refuted (worse,
// latency-bound at K=1024 / 1 block/CU). This is the structure's optimum
// of the variants measured on this shape (~595 TF).
// ---------------------------------------------------------------------------
template<int KD, int NCOLS, int MODE>
__global__ __launch_bounds__(256) void gemm_mfma(
    const unsigned short* __restrict__ A,
    const unsigned short* __restrict__ BT,
    const float* __restrict__ bias,
    unsigned short* __restrict__ Oq,
    unsigned short* __restrict__ Ok,
    unsigned short* __restrict__ Ov,
    float* __restrict__ Of)
{
    __shared__ __align__(16) unsigned short aS[128 * 64];
    __shared__ __align__(16) unsigned short bS[128 * 64];

    const int tid  = threadIdx.x;
    const int lane = tid & 63;
    const int wave = tid >> 6;
    const int row  = lane & 15;
    const int quad = lane >> 4;
    const int wm   = wave >> 1;
    const int wn   = wave & 1;

    // T1 XCD remap: HW dispatches linear id x-major, round-robin over 8 XCDs.
    constexpr int NT  = NCOLS / 128;          // N-tiles (24 or 8)
    constexpr int MT8 = (MROWS / 128) / 8;    // M-tiles per XCD chunk = 8
    const int orig = blockIdx.x + blockIdx.y * NT;
    const int xcd  = orig & 7;
    const int pos  = orig >> 3;               // position within XCD chunk
    const int nt   = pos >> 3;                // N-tile (pos / MT8)
    const int mtl  = pos & (MT8 - 1);         // local M-tile
    const int m0   = (xcd * MT8 + mtl) * 128;
    const int n0   = nt * 128;

    // staging geometry: one gload = 64 lanes x 16B = 8 rows x 64 k (128B/row)
    const int srow = lane >> 3;            // 0..7  local row
    const int c8   = lane & 7;             // 0..7  dest chunk (16B units)
    const int csw  = c8 ^ srow;            // pre-swizzled SOURCE chunk

    // hoisted global staging pointers (advance by 64 elements per K-step)
    const unsigned short* aG = A  + (size_t)(m0 + wave * 8 + srow) * KD + csw * 8;
    const unsigned short* bG = BT + (size_t)(n0 + wave * 8 + srow) * KD + csw * 8;

    f32x4 acc[4][4];
    const f32x4 z = {0.f, 0.f, 0.f, 0.f};
    #pragma unroll
    for (int i = 0; i < 4; i++)
        #pragma unroll
        for (int j = 0; j < 4; j++) acc[i][j] = z;

    for (int k0 = 0; k0 < KD; k0 += 64) {
        __syncthreads();   // all waves done reading previous tile
        #pragma unroll
        for (int c = 0; c < 4; c++) {
            gl_lds16(aG + c * (32 * KD), &aS[c * 2048 + wave * 512]);
            gl_lds16(bG + c * (32 * KD), &bS[c * 2048 + wave * 512]);
        }
        __syncthreads();   // drains vmcnt -> LDS valid
        aG += 64;
        bG += 64;

        #pragma unroll
        for (int ks = 0; ks < 2; ks++) {
            bf16x8 af[4], bf[4];
            const int cp = ((ks * 4 + quad) ^ (row & 7)) * 8;   // swizzled read chunk
            #pragma unroll
            for (int t = 0; t < 4; t++) {
                af[t] = *(const bf16x8*)(aS + (wm * 64 + t * 16 + row) * 64 + cp);
                bf[t] = *(const bf16x8*)(bS + (wn * 64 + t * 16 + row) * 64 + cp);
            }
            #pragma unroll
            for (int i = 0; i < 4; i++)
                #pragma unroll
                for (int j = 0; j < 4; j++)
                    acc[i][j] = __builtin_amdgcn_mfma_f32_16x16x32_bf16(af[i], bf[j], acc[i][j], 0, 0, 0);
        }
    }

    if (MODE == 0) {
        #pragma unroll
        for (int j = 0; j < 4; j++) {
            const int n  = n0 + wn * 64 + j * 16 + row;
            const float bi = bias[n];
            const int which = n >> 10;
            const int rem   = n & 1023;
            const int h     = rem >> 6;
            const int d     = rem & 63;
            #pragma unroll
            for (int i = 0; i < 4; i++) {
                const int mbase = m0 + wm * 64 + i * 16 + quad * 4;
                #pragma unroll
                for (int r = 0; r < 4; r++) {
                    const int m = mbase + r;
                    const int b = m >> 11;
                    const int t = m & 2047;
                    const int bh = b * NHEADS + h;
                    const float v = acc[i][j][r] + bi;
                    if (which == 0) {
                        Oq[((size_t)bh * T_SEQ + t) * HDIM + d] = f2b(v * QSCALE);
                    } else if (which == 1) {
                        Ok[((size_t)bh * T_SEQ + t) * HDIM + d] = f2b(v);
                    } else {
                        Ov[((size_t)bh * HDIM + d) * T_SEQ + t] = f2b(v);
                    }
                }
            }
        }
    } else {
        #pragma unroll
        for (int j = 0; j < 4; j++) {
            const int n  = n0 + wn * 64 + j * 16 + row;
            const float bi = bias[n];
            #pragma unroll
            for (int i = 0; i < 4; i++) {
                const int mbase = m0 + wm * 64 + i * 16 + quad * 4;
                #pragma unroll
                for (int r = 0; r < 4; r++)
                    Of[(size_t)(mbase + r) * NCOLS + n] = acc[i][j][r] + bi;
            }
        }
    }
}

// ---------------------------------------------------------------------------
// MFMA flash attention — R19 EXACT (verified 85.9us, best of 7 attn variants
// tried): ONE tile per wave, one-sided blocks. Block (bh, by): i = 15-by
// (longest first), q-rows [128i, 128i+128), 8 waves x 16 rows; kend =
// 128(i+1). Grid (64,16) = 1024 blocks -> 4/CU. Stride-72 LDS pad (R24's
// XOR swizzle refuted: conflicts 4.2M -> 8.45M, dur +6.7us; the per-row
// 4-bank rotation of stride-72 spreads this b128/b64 mix better).
// Defer-max + tree-max kept; no setprio (m190 lockstep null).
// ---------------------------------------------------------------------------
__global__ __launch_bounds__(512, 4) void attn_mfma(
    const unsigned short* __restrict__ Q,   // [bh][t][64] bf16 (scaled, log2e)
    const unsigned short* __restrict__ K,   // [bh][t][64] bf16
    const unsigned short* __restrict__ VT,  // [bh][64][T] bf16
    unsigned short* __restrict__ Out)       // [B*T][DMODEL] bf16
{
    __shared__ __align__(16) unsigned short kS[2][64 * 72];
    __shared__ __align__(16) unsigned short vS[2][64 * 72];

    const int tid  = threadIdx.x;
    const int lane = tid & 63;
    const int wave = tid >> 6;       // 0..7
    const int row  = lane & 15;
    const int quad = lane >> 4;

    const int bh = blockIdx.x;
    const int b  = bh >> 4;
    const int h  = bh & 15;
    const int i  = 15 - (int)blockIdx.y;       // longest blocks first
    const int q0 = 128 * i + 16 * wave;        // this wave's 16 q-rows
    const int kend = 128 * i + 128;            // WG-uniform loop bound

    const size_t qkbase = (size_t)bh * T_SEQ * HDIM;
    const size_t vtbase = (size_t)bh * HDIM * T_SEQ;

    // staging geometry: 512 threads cover one 64x64 tile per operand
    const int krow0 = tid >> 3;          // 0..63
    const int c0    = tid & 7;           // 0..7
    const int lds0  = krow0 * 72 + c0 * 8;
    const int flat0 = tid * 8;           // = krow0*64 + c0*8

    // Q fragments
    const unsigned short* qp = Q + qkbase + (size_t)(q0 + row) * HDIM + quad * 8;
    const bf16x8 qf0 = *(const bf16x8*)qp;
    const bf16x8 qf1 = *(const bf16x8*)(qp + 32);

    const f32x4 z = {0.f, 0.f, 0.f, 0.f};
    f32x4 o[4] = {z, z, z, z};
    float m_ = -1e30f, l_ = 0.f;

    // prefetch tile 0
    uint4 pk0 = *(const uint4*)(K  + qkbase + flat0);
    uint4 pv0 = *(const uint4*)(VT + vtbase + (size_t)krow0 * T_SEQ + c0 * 8);

    int buf = 0;
    for (int kb = 0; kb < kend; kb += 64) {
        // write staged tile to LDS[buf]
        *(uint4*)&kS[buf][lds0] = pk0;
        *(uint4*)&vS[buf][lds0] = pv0;
        __syncthreads();

        // prefetch next tile (overlaps with compute below)
        if (kb + 64 < kend) {
            const int kn = kb + 64;
            pk0 = *(const uint4*)(K  + qkbase + (size_t)kn * HDIM + flat0);
            pv0 = *(const uint4*)(VT + vtbase + (size_t)krow0 * T_SEQ + kn + c0 * 8);
        }

        const bool act = (kb <= q0);         // wave-uniform

        if (act) {
            // ---- QK^T from LDS K tile ----
            f32x4 sg[4];
            bf16x4 pf[4];
            #pragma unroll
            for (int s = 0; s < 4; s++) {
                const int kbs = kb + s * 16;
                if (kbs <= q0) {
                    const unsigned short* kp = &kS[buf][(s * 16 + row) * 72 + quad * 8];
                    const bf16x8 kf0 = *(const bf16x8*)kp;
                    const bf16x8 kf1 = *(const bf16x8*)(kp + 32);
                    f32x4 t = z;
                    t = __builtin_amdgcn_mfma_f32_16x16x32_bf16(kf0, qf0, t, 0, 0, 0);
                    t = __builtin_amdgcn_mfma_f32_16x16x32_bf16(kf1, qf1, t, 0, 0, 0);
                    if (kbs == q0) {
                        #pragma unroll
                        for (int r = 0; r < 4; r++)
                            if (quad * 4 + r > row) t[r] = -1e30f;
                    }
                    sg[s] = t;
                } else {
                    #pragma unroll
                    for (int r = 0; r < 4; r++) sg[s][r] = -1e30f;
                }
            }
            online_softmax(sg, m_, l_, o, pf);

            // ---- PV from LDS V^T tile ----
            #pragma unroll
            for (int s = 0; s < 4; s++) {
                const int kbs = kb + s * 16;
                if (kbs <= q0) {
                    #pragma unroll
                    for (int dt = 0; dt < 4; dt++) {
                        const bf16x4 vf = *(const bf16x4*)&vS[buf][
                            (dt * 16 + row) * 72 + (s * 2 + (quad >> 1)) * 8 + (quad & 1) * 4];
                        o[dt] = __builtin_amdgcn_mfma_f32_16x16x16bf16_1k(vf, pf[s], o[dt], 0, 0, 0);
                    }
                }
            }
        }

        buf ^= 1;
    }

    // ---- epilogue ----
    {
        const float rl = 1.f / l_;
        unsigned short* op = Out + ((size_t)(b * T_SEQ + q0 + row)) * DMODEL + h * HDIM + quad * 4;
        #pragma unroll
        for (int dt = 0; dt < 4; dt++) {
            uint2 u;
            u.x = pack2(o[dt][0] * rl, o[dt][1] * rl);
            u.y = pack2(o[dt][2] * rl, o[dt][3] * rl);
            *(uint2*)(op + dt * 16) = u;
        }
    }
}

extern "C" void kernel_launch(void* const* d_in, const int* in_sizes, int n_in,
                              void* d_out, int out_size, void* d_ws, size_t ws_size,
                              hipStream_t stream)
{
    const float* x    = (const float*)d_in[0];
    const float* Wqkv = (const float*)d_in[1];
    const float* bqkv = (const float*)d_in[2];
    const float* Wout = (const float*)d_in[3];
    const float* bout = (const float*)d_in[4];
    float* out = (float*)d_out;

    // workspace (MiB offsets): xb 0..16 | WqkvT 16..22 | WoutT 22..24 |
    // Qb 24..40 | Kb 40..56 | Vt 56..72 | Ab 72..88
    char* ws = (char*)d_ws;
    unsigned short* xb    = (unsigned short*)(ws + (size_t)0  * 1024 * 1024);
    unsigned short* WqkvT = (unsigned short*)(ws + (size_t)16 * 1024 * 1024);
    unsigned short* WoutT = (unsigned short*)(ws + (size_t)22 * 1024 * 1024);
    unsigned short* Qb    = (unsigned short*)(ws + (size_t)24 * 1024 * 1024);
    unsigned short* Kb    = (unsigned short*)(ws + (size_t)40 * 1024 * 1024);
    unsigned short* Vt    = (unsigned short*)(ws + (size_t)56 * 1024 * 1024);
    unsigned short* Ab    = (unsigned short*)(ws + (size_t)72 * 1024 * 1024);

    // 0) merged prep: x->bf16 + both weight transposes (ONE launch, was 3)
    prep<<<dim3(8192 + 3072 + 1024), 256, 0, stream>>>(
        x, xb, Wqkv, WqkvT, Wout, WoutT);

    // 1) qkv = x @ W_qkv + b_qkv -> Qb (scaled, log2e folded), Kb, Vt
    gemm_mfma<DMODEL, 3 * DMODEL, 0><<<dim3(3 * DMODEL / 128, MROWS / 128), 256, 0, stream>>>(
        xb, WqkvT, bqkv, Qb, Kb, Vt, nullptr);

    // 2) causal MFMA flash attention -> Ab bf16 (16 blocks/head, 8 waves, 1 tile/wave)
    attn_mfma<<<dim3(BATCH * NHEADS, 16), 512, 0, stream>>>(Qb, Kb, Vt, Ab);

    // 3) out = Ab @ W_out + b_out (fp32 out)
    gemm_mfma<DMODEL, DMODEL, 1><<<dim3(DMODEL / 128, MROWS / 128), 256, 0, stream>>>(
        Ab, WoutT, bout, nullptr, nullptr, nullptr, out);
}